// Round 4
// baseline (348.176 us; speedup 1.0000x reference)
//
#include <hip/hip_runtime.h>
#include <hip/hip_bf16.h>
#include <math.h>

// A1SparseCoding: STFT(512,160,hann,center=False) -> |.| -> per-sample norm ->
// LCA (50 iters, lam=0.5, tau=10) -> softshrink(u)
// B=8192, SEG=3200, T=17 frames, F=257 freqs, K=17*257=4369 (pad 4384), N=128 bases.
// spec stored [b][t*257+f]; D's columns permuted identically (dot products invariant).
// STFT: two real frames packed as one complex FFT (a+ib), radix-8 DIT, fp32,
// twiddles/window from LDS tables (no transcendentals in the hot loop),
// conj-unpack via shfl. GEMM: MFMA frags direct from global, 3-deep rolling prefetch.

typedef short bf16x8 __attribute__((ext_vector_type(8)));
typedef float f32x4  __attribute__((ext_vector_type(4)));

#define TWO_PI_OVER_512 0.01227184630f

__device__ __forceinline__ unsigned short f2bf(float f){
  unsigned int u = __float_as_uint(f);
  u += 0x7FFFu + ((u >> 16) & 1u);      // RNE; inputs finite
  return (unsigned short)(u >> 16);
}
__device__ __forceinline__ float sshrink(float u){
  float a = fabsf(u) - 0.5f;
  return a > 0.0f ? copysignf(a, u) : 0.0f;
}

// ---------------- P0: tables: digit-reversed window + W_512 ------------------
__global__ void k_tables(float* __restrict__ wing, float2* __restrict__ twg){
  int p = blockIdx.x*blockDim.x + threadIdx.x;
  if (p < 512){
    int r9 = ((p & 7) << 6) | (p & 56) | (p >> 6);        // base-8 digit reversal
    wing[p] = 0.5f - 0.5f*cosf((float)r9 * TWO_PI_OVER_512);  // periodic hann, rev order
    float t = (float)p * TWO_PI_OVER_512;
    twg[p] = make_float2(cosf(t), sinf(t));               // W_512^p = c - i s
  }
}

// ---------------- P1: D prep: Dbf[n][k'] bf16 via LDS permute + rowsum -------
__global__ __launch_bounds__(256) void k_dprep(const float* __restrict__ D,
    unsigned short* __restrict__ Dbf, float* __restrict__ rowsum){
  __shared__ float row[4369];
  __shared__ float rs[256];
  const int n = blockIdx.x, tid = threadIdx.x;
  float acc = 0.0f;
  for (int k = tid; k < 4369; k += 256){
    float v = D[(size_t)n*4369 + k];          // coalesced
    row[k] = v;
    acc += v;
  }
  rs[tid] = acc;
  __syncthreads();
  #pragma unroll
  for (int s = 128; s > 0; s >>= 1){
    if (tid < s) rs[tid] += rs[tid + s];
    __syncthreads();
  }
  if (tid == 0) rowsum[n] = rs[0];
  // permuted bf16 row: k' = t*257+f  <-  src = f*17+t ; packed ushort4 stores
  for (int i = tid; i < 1096; i += 256){
    int k0 = i*4;
    ushort4 pk;
    unsigned short v[4];
    #pragma unroll
    for (int u = 0; u < 4; u++){
      int kp = k0 + u;
      unsigned short r = 0;
      if (kp < 4369){
        int t = kp / 257, f = kp - t*257;
        r = f2bf(row[f*17 + t]);
      }
      v[u] = r;
    }
    pk.x = v[0]; pk.y = v[1]; pk.z = v[2]; pk.w = v[3];
    *(ushort4*)(Dbf + (size_t)n*4384 + k0) = pk;
  }
}

// ---------------- P2: gram = Dbf·Dbfᵀ partials via MFMA (k-split 8) ----------
__global__ __launch_bounds__(64) void k_gram_mm(const unsigned short* __restrict__ Dbf,
    float* __restrict__ pgram){
  const int x = blockIdx.x;                   // 16-row strip, 0..7
  const int ks = blockIdx.y;                  // 0..7
  const int lane = threadIdx.x;
  const int c = lane & 15, q = lane >> 4;
  const unsigned short* ap = Dbf + (size_t)(x*16 + c)*4384 + q*8;
  const unsigned short* bp = Dbf + (size_t)c*4384 + q*8;
  const int t0 = ks*17, t1 = (ks == 7) ? 137 : t0 + 17;
  f32x4 acc[8];
  #pragma unroll
  for (int nt = 0; nt < 8; nt++) acc[nt] = (f32x4){0.f,0.f,0.f,0.f};
  for (int tt = t0; tt < t1; tt++){
    const int k0 = tt*32;
    bf16x8 af = *(const bf16x8*)(ap + k0);
    #pragma unroll
    for (int nt = 0; nt < 8; nt++){
      bf16x8 bfr = *(const bf16x8*)(bp + (size_t)nt*16*4384 + k0);
      acc[nt] = __builtin_amdgcn_mfma_f32_16x16x32_bf16(af, bfr, acc[nt], 0, 0, 0);
    }
  }
  // C layout: row = q*4+r (gram row within strip), col = c (gram col within nt)
  #pragma unroll
  for (int nt = 0; nt < 8; nt++)
    #pragma unroll
    for (int r = 0; r < 4; r++)
      pgram[(size_t)(ks*128 + x*16 + q*4 + r)*128 + nt*16 + c] = acc[nt][r];
}
// deterministic fixed-order sum -> exactly symmetric (MFMA k-order identical for (x,y)/(y,x))
__global__ __launch_bounds__(128) void k_gram_fin(const float* __restrict__ pgram,
    unsigned short* __restrict__ gram_bf){
  const int x = blockIdx.x, y = threadIdx.x;
  float g = ((pgram[(size_t)x*128+y]        + pgram[(size_t)(128+x)*128+y])
          +  (pgram[(size_t)(256+x)*128+y]  + pgram[(size_t)(384+x)*128+y]))
          + ((pgram[(size_t)(512+x)*128+y]  + pgram[(size_t)(640+x)*128+y])
          +  (pgram[(size_t)(768+x)*128+y]  + pgram[(size_t)(896+x)*128+y]));
  if (x == y) g -= 1.0f;
  gram_bf[x*136 + y] = f2bf(g);
}

// ---------------- radix-8 butterfly (DIT), in registers ----------------------
__device__ __forceinline__ void dft8(float xr[8], float xi[8]){
  const float C = 0.70710678118654752f;
  float t0r = xr[0]+xr[4], t0i = xi[0]+xi[4];
  float t1r = xr[0]-xr[4], t1i = xi[0]-xi[4];
  float t2r = xr[2]+xr[6], t2i = xi[2]+xi[6];
  float t3r = xr[2]-xr[6], t3i = xi[2]-xi[6];
  float e0r = t0r+t2r, e0i = t0i+t2i;
  float e2r = t0r-t2r, e2i = t0i-t2i;
  float e1r = t1r+t3i, e1i = t1i-t3r;
  float e3r = t1r-t3i, e3i = t1i+t3r;
  float s0r = xr[1]+xr[5], s0i = xi[1]+xi[5];
  float s1r = xr[1]-xr[5], s1i = xi[1]-xi[5];
  float s2r = xr[3]+xr[7], s2i = xi[3]+xi[7];
  float s3r = xr[3]-xr[7], s3i = xi[3]-xi[7];
  float o0r = s0r+s2r, o0i = s0i+s2i;
  float o2r = s0r-s2r, o2i = s0i-s2i;
  float o1r = s1r+s3i, o1i = s1i-s3r;
  float o3r = s1r-s3i, o3i = s1i+s3r;
  xr[0] = e0r+o0r; xi[0] = e0i+o0i;
  xr[4] = e0r-o0r; xi[4] = e0i-o0i;
  float w1r = C*(o1r+o1i), w1i = C*(o1i-o1r);
  xr[1] = e1r+w1r; xi[1] = e1i+w1i;
  xr[5] = e1r-w1r; xi[5] = e1i-w1i;
  xr[2] = e2r+o2i; xi[2] = e2i-o2r;
  xr[6] = e2r-o2i; xi[6] = e2i+o2r;
  float w3r = C*(o3i-o3r), w3i = -C*(o3r+o3i);
  xr[3] = e3r+w3r; xi[3] = e3i+w3i;
  xr[7] = e3r-w3r; xi[7] = e3i-w3i;
}

// ---------------- K1: STFT magnitude + moment atomics ------------------------
// 4 waves/WG, each wave = one FRAME PAIR packed a+ib; private LDS Z slice.
// One barrier total (table staging); FFT phases barrier-free.
__global__ __launch_bounds__(256) void k_stft(const float* __restrict__ audio,
    const float* __restrict__ wing, const float2* __restrict__ twg,
    unsigned short* __restrict__ spec, float* __restrict__ sums){
  __shared__ float2 twl[512];                 // W_512 table, 4 KB
  __shared__ float  winl[512];                // hann (digit-rev order), 2 KB
  __shared__ float2 zb[4][616];               // per-wave FFT scratch
  const int tid = threadIdx.x;
  ((float4*)twl)[tid] = ((const float4*)twg)[tid];          // 256 x 16B = 4 KB
  if (tid < 128) ((float4*)winl)[tid] = ((const float4*)wing)[tid]; // 2 KB
  __syncthreads();
  const int wid = tid >> 6;
  const int L = tid & 63;
  float2* Z = zb[wid];
  const int pair = blockIdx.x*4 + wid;        // 0..69631
  const int fr0 = pair*2;
  const int b0 = fr0/17, t0 = fr0 - b0*17;
  const int fr1 = fr0 + 1;
  const int b1 = fr1/17, t1 = fr1 - b1*17;
  const float* sA = audio + (size_t)b0*3200 + t0*160;
  const float* sB = audio + (size_t)b1*3200 + t1*160;
  float xr[8], xi[8];
  // fused digit-reversed load + window (LDS) ; idx=8L+e -> r9 = baseRev+64e
  {
    const int baseRev = ((L & 7) << 3) | (L >> 3);
    float4 w0 = *(const float4*)(winl + 8*L);
    float4 w1 = *(const float4*)(winl + 8*L + 4);
    float wv[8] = {w0.x,w0.y,w0.z,w0.w,w1.x,w1.y,w1.z,w1.w};
    #pragma unroll
    for (int e = 0; e < 8; e++){
      int r9 = baseRev + (e << 6);
      xr[e] = sA[r9]*wv[e];
      xi[e] = sB[r9]*wv[e];
    }
  }
  dft8(xr, xi);
  {
    int s0 = 9*L + 5*(L >> 3);                // slot(8L), e contiguous
    #pragma unroll
    for (int e = 0; e < 8; e++) Z[s0 + e] = make_float2(xr[e], xi[e]);
  }
  // stage 1: i = g*64 + j + 8e -> slot = 77g + j + 9e ; W_64^{je} = W_512^{8je}
  {
    int j = L & 7, g = L >> 3;
    int sb = 77*g + j;
    #pragma unroll
    for (int e = 0; e < 8; e++){
      float2 z = Z[sb + 9*e];
      xr[e] = z.x; xi[e] = z.y;
    }
    #pragma unroll
    for (int e = 1; e < 8; e++){
      float2 w = twl[8*j*e];                  // (c, s): W = c - i s
      float a = xr[e], b = xi[e];
      xr[e] = a*w.x + b*w.y;
      xi[e] = b*w.x - a*w.y;
    }
    dft8(xr, xi);
    #pragma unroll
    for (int e = 0; e < 8; e++) Z[sb + 9*e] = make_float2(xr[e], xi[e]);
  }
  // stage 2: i = L + 64e -> slot = L + (L>>3) + 77e ; lane L ends with Z[k=L+64f]
  {
    int sb = L + (L >> 3);
    #pragma unroll
    for (int e = 0; e < 8; e++){
      float2 z = Z[sb + 77*e];
      xr[e] = z.x; xi[e] = z.y;
    }
    #pragma unroll
    for (int e = 1; e < 8; e++){
      float2 w = twl[L*e];                    // L*e <= 441
      float a = xr[e], b = xi[e];
      xr[e] = a*w.x + b*w.y;
      xi[e] = b*w.x - a*w.y;
    }
    dft8(xr, xi);
  }
  // conj-partner exchange: partner of k=L+64f is lane (64-L)&63, reg 7-f (L>=1)
  float pr[4], pi[4];
  {
    const int partner = (64 - L) & 63;
    #pragma unroll
    for (int f = 0; f < 4; f++){
      pr[f] = __shfl(xr[7-f], partner);
      pi[f] = __shfl(xi[7-f], partner);
    }
    if (L == 0){                              // lane 0: partner regs are own (8-f)&7
      pr[0] = xr[0]; pi[0] = xi[0];
      pr[1] = xr[7]; pi[1] = xi[7];
      pr[2] = xr[6]; pi[2] = xi[6];
      pr[3] = xr[5]; pi[3] = xi[5];
    }
  }
  unsigned short* dA = spec + (size_t)b0*4384 + t0*257;
  unsigned short* dB = spec + (size_t)b1*4384 + t1*257;
  float s1A = 0.f, s2A = 0.f, s1B = 0.f, s2B = 0.f;
  #pragma unroll
  for (int f = 0; f < 4; f++){
    int k = L + 64*f;
    float ar = xr[f] + pr[f], ai = xi[f] - pi[f];
    float br = xi[f] + pi[f], bi = pr[f] - xr[f];
    float magA = 0.5f*sqrtf(ar*ar + ai*ai);
    float magB = 0.5f*sqrtf(br*br + bi*bi);
    dA[k] = f2bf(magA);
    dB[k] = f2bf(magB);
    s1A += magA; s2A += magA*magA;
    s1B += magB; s2B += magB*magB;
  }
  if (L == 0){                                // k=256: Xa=Re(Z[256]), Xb=Im(Z[256])
    float magA = fabsf(xr[4]);
    float magB = fabsf(xi[4]);
    dA[256] = f2bf(magA);
    dB[256] = f2bf(magB);
    s1A += magA; s2A += magA*magA;
    s1B += magB; s2B += magB*magB;
  }
  #pragma unroll
  for (int off = 32; off > 0; off >>= 1){
    s1A += __shfl_down(s1A, off);
    s2A += __shfl_down(s2A, off);
    s1B += __shfl_down(s1B, off);
    s2B += __shfl_down(s2B, off);
  }
  if (L == 0){
    atomicAdd(&sums[b0], s1A);
    atomicAdd(&sums[8192 + b0], s2A);
    atomicAdd(&sums[b1], s1B);
    atomicAdd(&sums[8192 + b1], s2B);
  }
  if (t0 == 0 && L < 15) spec[(size_t)b0*4384 + 4369 + L] = 0;
  if (t1 == 0 && L < 15) spec[(size_t)b1*4384 + 4369 + L] = 0;
}

// ---------------- K4: partial GEMM spec·Dᵀ, 3-deep rolling prefetch ----------
#define LDA(dst, tt)  dst = *(const bf16x8*)(ap + (tt)*32)
#define LDB(dst, tt)  _Pragma("unroll") \
  for (int nt = 0; nt < 8; nt++) dst[nt] = *(const bf16x8*)(bp + (size_t)nt*16*4384 + (tt)*32)
#define MM(a, b) _Pragma("unroll") \
  for (int nt = 0; nt < 8; nt++) acc[nt] = __builtin_amdgcn_mfma_f32_16x16x32_bf16(a, b[nt], acc[nt], 0, 0, 0)

__global__ __launch_bounds__(128) void k_gemm(const unsigned short* __restrict__ spec,
    const unsigned short* __restrict__ Dbf, float* __restrict__ part){
  const int mtile = blockIdx.x;               // 0..255
  const int ks = blockIdx.y;                  // 0..3
  const int wv = threadIdx.x >> 6;
  const int lane = threadIdx.x & 63;
  const int c = lane & 15, q = lane >> 4;
  const int m0 = mtile*32 + wv*16;
  const unsigned short* ap = spec + (size_t)(m0 + c)*4384 + q*8;
  const unsigned short* bp = Dbf + (size_t)c*4384 + q*8;
  const int t0 = ks*35, t1 = (ks == 3) ? 137 : (ks*35 + 35);
  const int tl = t1 - 1;
  f32x4 acc[8];
  #pragma unroll
  for (int nt = 0; nt < 8; nt++) acc[nt] = (f32x4){0.f,0.f,0.f,0.f};
  bf16x8 a0, a1, a2, b0[8], b1[8], b2[8];
  LDA(a0, t0);              LDB(b0, t0);
  LDA(a1, t0+1);            LDB(b1, t0+1);    // t0+1 <= tl always (span >= 32)
  LDA(a2, t0+2);            LDB(b2, t0+2);
  int tt = t0;
  for (; tt + 3 <= t1; tt += 3){              // span = 35 or 32 -> remainder 2
    int p0 = (tt+3 < t1) ? tt+3 : tl;
    int p1 = (tt+4 < t1) ? tt+4 : tl;
    int p2 = (tt+5 < t1) ? tt+5 : tl;
    MM(a0, b0);  LDA(a0, p0);  LDB(b0, p0);
    MM(a1, b1);  LDA(a1, p1);  LDB(b1, p1);
    MM(a2, b2);  LDA(a2, p2);  LDB(b2, p2);
  }
  MM(a0, b0);                                  // remainder == 2 for both spans
  MM(a1, b1);
  float* base = part + (size_t)ks*1048576 + m0 + q*4;
  #pragma unroll
  for (int nt = 0; nt < 8; nt++)
    *(f32x4*)(base + (size_t)(nt*16 + c)*8192) = acc[nt];
}

// ---------------- K5: LCA, 50 iters. rᵀ = G·aᵀ; 4 waves x 32 gram rows ------
// 512 blocks x 256 thr: block = 16 samples; wave wv owns rows [wv*32, wv*32+32).
// a exchanged via double-buffered LDS, ONE barrier per iter.
__global__ __launch_bounds__(256) void k_lca(const float* __restrict__ part,
    const unsigned short* __restrict__ gram_bf, const float* __restrict__ rowsum,
    const float* __restrict__ sums, float* __restrict__ out){
  __shared__ unsigned short A[2][16*136];
  const int tid = threadIdx.x, wv = tid >> 6, lane = tid & 63;
  const int c = lane & 15, q = lane >> 4;
  const int sg = blockIdx.x*16 + c;
  const float S1 = sums[sg], S2 = sums[8192 + sg];
  const float mus = S1 / 4369.0f;
  float var = (S2 - S1*S1/4369.0f) / 4368.0f;
  var = fmaxf(var, 0.0f);
  const float invs = 1.0f / (sqrtf(var) + 1e-8f);
  const int nb = wv*32;
  bf16x8 Gf[2][4];                            // A-frags of G rows [nb, nb+32)
  #pragma unroll
  for (int rt = 0; rt < 2; rt++)
    #pragma unroll
    for (int kt = 0; kt < 4; kt++)
      Gf[rt][kt] = *(const bf16x8*)(gram_bf + (size_t)(nb + rt*16 + c)*136 + kt*32 + q*8);
  f32x4 U[2], Bb[2];
  #pragma unroll
  for (int rt = 0; rt < 2; rt++){
    #pragma unroll
    for (int r = 0; r < 4; r++){
      int n = nb + rt*16 + q*4 + r;
      float S = part[(size_t)n*8192 + sg]
              + part[(size_t)1048576 + (size_t)n*8192 + sg]
              + part[(size_t)2097152 + (size_t)n*8192 + sg]
              + part[(size_t)3145728 + (size_t)n*8192 + sg];
      Bb[rt][r] = invs * (S - mus * rowsum[n]);
      U[rt][r] = 0.0f;
    }
  }
  for (int it = 0; it < 50; it++){
    unsigned short* Ab = A[it & 1];
    #pragma unroll
    for (int rt = 0; rt < 2; rt++){
      ushort4 pk;
      pk.x = f2bf(sshrink(U[rt][0]));
      pk.y = f2bf(sshrink(U[rt][1]));
      pk.z = f2bf(sshrink(U[rt][2]));
      pk.w = f2bf(sshrink(U[rt][3]));
      *(ushort4*)(Ab + c*136 + nb + rt*16 + q*4) = pk;
    }
    __syncthreads();
    bf16x8 af[4];
    #pragma unroll
    for (int kt = 0; kt < 4; kt++)            // B-frag: aᵀ[k][sample=c]
      af[kt] = *(const bf16x8*)(Ab + c*136 + kt*32 + q*8);
    f32x4 R[2];
    R[0] = (f32x4){0.f,0.f,0.f,0.f};
    R[1] = (f32x4){0.f,0.f,0.f,0.f};
    #pragma unroll
    for (int kt = 0; kt < 4; kt++)            // kt outer: R[0],R[1] chains interleave
      #pragma unroll
      for (int rt = 0; rt < 2; rt++)
        R[rt] = __builtin_amdgcn_mfma_f32_16x16x32_bf16(Gf[rt][kt], af[kt], R[rt], 0, 0, 0);
    #pragma unroll
    for (int rt = 0; rt < 2; rt++){
      #pragma unroll
      for (int r = 0; r < 4; r++){
        float u = U[rt][r];
        U[rt][r] = u + (Bb[rt][r] - u - R[rt][r]) * 0.1f;
      }
    }
  }
  #pragma unroll
  for (int rt = 0; rt < 2; rt++){
    float4 o;
    o.x = sshrink(U[rt][0]);
    o.y = sshrink(U[rt][1]);
    o.z = sshrink(U[rt][2]);
    o.w = sshrink(U[rt][3]);
    *(float4*)(out + (size_t)sg*128 + nb + rt*16 + q*4) = o;
  }
}

// ---------------- launch ----------------
extern "C" void kernel_launch(void* const* d_in, const int* in_sizes, int n_in,
                              void* d_out, int out_size, void* d_ws, size_t ws_size,
                              hipStream_t stream){
  const float* audio = (const float*)d_in[0];   // 8192*3200
  const float* D     = (const float*)d_in[1];   // 128*4369
  float* out = (float*)d_out;                   // 8192*128 f32
  char* ws = (char*)d_ws;
  // workspace layout, total ~90.36 MB
  unsigned short* spec   = (unsigned short*)(ws);               // 71,827,456
  float*          part   = (float*)(ws + 71827456);             // 16,777,216
  unsigned short* Dbf    = (unsigned short*)(ws + 88604672);    // 1,122,304
  unsigned short* gram   = (unsigned short*)(ws + 89726976);    // 34,816
  float*          pgram  = (float*)(ws + 89761792);             // 524,288
  float*          rowsum = (float*)(ws + 90286080);             // 512
  float*          sums   = (float*)(ws + 90286592);             // 65,536 (s1 | s2)
  float*          wing   = (float*)(ws + 90352128);             // 2,048
  float2*         twg    = (float2*)(ws + 90354176);            // 4,096

  hipMemsetAsync(sums, 0, 65536, stream);       // ws is poisoned each launch
  k_tables  <<<2, 256, 0, stream>>>(wing, twg);
  k_stft    <<<17408, 256, 0, stream>>>(audio, wing, twg, spec, sums);
  k_dprep   <<<128, 256, 0, stream>>>(D, Dbf, rowsum);
  k_gram_mm <<<dim3(8, 8, 1), 64, 0, stream>>>(Dbf, pgram);
  k_gram_fin<<<128, 128, 0, stream>>>(pgram, gram);
  k_gemm    <<<dim3(256, 4, 1), 128, 0, stream>>>(spec, Dbf, part);
  k_lca     <<<512, 256, 0, stream>>>(part, gram, rowsum, sums, out);
}

// Round 5
// 301.794 us; speedup vs baseline: 1.1537x; 1.1537x over previous
//
#include <hip/hip_runtime.h>
#include <hip/hip_bf16.h>
#include <math.h>

// A1SparseCoding: STFT(512,160,hann,center=False) -> |.| -> per-sample norm ->
// LCA (50 iters, lam=0.5, tau=10) -> softshrink(u)
// B=8192, SEG=3200, T=17 frames, F=257 freqs, K=17*257=4369 (pad 4384), N=128 bases.
// spec stored [b][t*257+f]; D's columns permuted identically (dot products invariant).
// STFT: two real frames packed as one complex FFT (a+ib), radix-8 DIT, fp32,
// twiddles via 2-transcendental rotor recurrence per stage (no tables, no LDS gathers).
// Moments (s1,s2) computed in k_gemm via extra MFMAs (ones-frag / X·Xᵀ diagonal),
// per-ks partials summed deterministically in k_lca. No atomics, no memset.

typedef short bf16x8 __attribute__((ext_vector_type(8)));
typedef float f32x4  __attribute__((ext_vector_type(4)));

#define TWO_PI_OVER_512 0.01227184630f
#define TWO_PI_OVER_64  0.09817477042f
#define C8 0.70710678118654752f

__device__ __forceinline__ unsigned short f2bf(float f){
  unsigned int u = __float_as_uint(f);
  u += 0x7FFFu + ((u >> 16) & 1u);      // RNE; inputs finite
  return (unsigned short)(u >> 16);
}
__device__ __forceinline__ float sshrink(float u){
  float a = fabsf(u) - 0.5f;
  return a > 0.0f ? copysignf(a, u) : 0.0f;
}

// ---------------- P1: D prep: Dbf[n][k'] bf16 via LDS permute + rowsum -------
__global__ __launch_bounds__(256) void k_dprep(const float* __restrict__ D,
    unsigned short* __restrict__ Dbf, float* __restrict__ rowsum){
  __shared__ float row[4369];
  __shared__ float rs[256];
  const int n = blockIdx.x, tid = threadIdx.x;
  float acc = 0.0f;
  for (int k = tid; k < 4369; k += 256){
    float v = D[(size_t)n*4369 + k];          // coalesced
    row[k] = v;
    acc += v;
  }
  rs[tid] = acc;
  __syncthreads();
  #pragma unroll
  for (int s = 128; s > 0; s >>= 1){
    if (tid < s) rs[tid] += rs[tid + s];
    __syncthreads();
  }
  if (tid == 0) rowsum[n] = rs[0];
  // permuted bf16 row: k' = t*257+f  <-  src = f*17+t ; packed ushort4 stores
  for (int i = tid; i < 1096; i += 256){
    int k0 = i*4;
    ushort4 pk;
    unsigned short v[4];
    #pragma unroll
    for (int u = 0; u < 4; u++){
      int kp = k0 + u;
      unsigned short r = 0;
      if (kp < 4369){
        int t = kp / 257, f = kp - t*257;
        r = f2bf(row[f*17 + t]);
      }
      v[u] = r;
    }
    pk.x = v[0]; pk.y = v[1]; pk.z = v[2]; pk.w = v[3];
    *(ushort4*)(Dbf + (size_t)n*4384 + k0) = pk;
  }
}

// ---------------- P2: gram = Dbf·Dbfᵀ partials via MFMA (k-split 8) ----------
__global__ __launch_bounds__(64) void k_gram_mm(const unsigned short* __restrict__ Dbf,
    float* __restrict__ pgram){
  const int x = blockIdx.x;                   // 16-row strip, 0..7
  const int ks = blockIdx.y;                  // 0..7
  const int lane = threadIdx.x;
  const int c = lane & 15, q = lane >> 4;
  const unsigned short* ap = Dbf + (size_t)(x*16 + c)*4384 + q*8;
  const unsigned short* bp = Dbf + (size_t)c*4384 + q*8;
  const int t0 = ks*17, t1 = (ks == 7) ? 137 : t0 + 17;
  f32x4 acc[8];
  #pragma unroll
  for (int nt = 0; nt < 8; nt++) acc[nt] = (f32x4){0.f,0.f,0.f,0.f};
  for (int tt = t0; tt < t1; tt++){
    const int k0 = tt*32;
    bf16x8 af = *(const bf16x8*)(ap + k0);
    #pragma unroll
    for (int nt = 0; nt < 8; nt++){
      bf16x8 bfr = *(const bf16x8*)(bp + (size_t)nt*16*4384 + k0);
      acc[nt] = __builtin_amdgcn_mfma_f32_16x16x32_bf16(af, bfr, acc[nt], 0, 0, 0);
    }
  }
  // C layout: row = q*4+r (gram row within strip), col = c (gram col within nt)
  #pragma unroll
  for (int nt = 0; nt < 8; nt++)
    #pragma unroll
    for (int r = 0; r < 4; r++)
      pgram[(size_t)(ks*128 + x*16 + q*4 + r)*128 + nt*16 + c] = acc[nt][r];
}
// deterministic fixed-order sum -> exactly symmetric (MFMA k-order identical for (x,y)/(y,x))
__global__ __launch_bounds__(128) void k_gram_fin(const float* __restrict__ pgram,
    unsigned short* __restrict__ gram_bf){
  const int x = blockIdx.x, y = threadIdx.x;
  float g = ((pgram[(size_t)x*128+y]        + pgram[(size_t)(128+x)*128+y])
          +  (pgram[(size_t)(256+x)*128+y]  + pgram[(size_t)(384+x)*128+y]))
          + ((pgram[(size_t)(512+x)*128+y]  + pgram[(size_t)(640+x)*128+y])
          +  (pgram[(size_t)(768+x)*128+y]  + pgram[(size_t)(896+x)*128+y]));
  if (x == y) g -= 1.0f;
  gram_bf[x*136 + y] = f2bf(g);
}

// ---------------- radix-8 butterfly (DIT), in registers ----------------------
__device__ __forceinline__ void dft8(float xr[8], float xi[8]){
  const float C = 0.70710678118654752f;
  float t0r = xr[0]+xr[4], t0i = xi[0]+xi[4];
  float t1r = xr[0]-xr[4], t1i = xi[0]-xi[4];
  float t2r = xr[2]+xr[6], t2i = xi[2]+xi[6];
  float t3r = xr[2]-xr[6], t3i = xi[2]-xi[6];
  float e0r = t0r+t2r, e0i = t0i+t2i;
  float e2r = t0r-t2r, e2i = t0i-t2i;
  float e1r = t1r+t3i, e1i = t1i-t3r;
  float e3r = t1r-t3i, e3i = t1i+t3r;
  float s0r = xr[1]+xr[5], s0i = xi[1]+xi[5];
  float s1r = xr[1]-xr[5], s1i = xi[1]-xi[5];
  float s2r = xr[3]+xr[7], s2i = xi[3]+xi[7];
  float s3r = xr[3]-xr[7], s3i = xi[3]-xi[7];
  float o0r = s0r+s2r, o0i = s0i+s2i;
  float o2r = s0r-s2r, o2i = s0i-s2i;
  float o1r = s1r+s3i, o1i = s1i-s3r;
  float o3r = s1r-s3i, o3i = s1i+s3r;
  xr[0] = e0r+o0r; xi[0] = e0i+o0i;
  xr[4] = e0r-o0r; xi[4] = e0i-o0i;
  float w1r = C*(o1r+o1i), w1i = C*(o1i-o1r);
  xr[1] = e1r+w1r; xi[1] = e1i+w1i;
  xr[5] = e1r-w1r; xi[5] = e1i-w1i;
  xr[2] = e2r+o2i; xi[2] = e2i-o2r;
  xr[6] = e2r-o2i; xi[6] = e2i+o2r;
  float w3r = C*(o3i-o3r), w3i = -C*(o3r+o3i);
  xr[3] = e3r+w3r; xi[3] = e3i+w3i;
  xr[7] = e3r-w3r; xi[7] = e3i-w3i;
}

// ---------------- K1: STFT magnitude -----------------------------------------
// 4 waves/WG, each wave = one FRAME PAIR packed a+ib; private LDS Z slice;
// zero barriers. Twiddles: 2 transcendentals/stage + complex-mul recurrence.
__global__ __launch_bounds__(256) void k_stft(const float* __restrict__ audio,
    unsigned short* __restrict__ spec){
  __shared__ float2 zb[4][616];
  const int tid = threadIdx.x;
  const int wid = tid >> 6;
  const int L = tid & 63;
  float2* Z = zb[wid];
  const int pair = blockIdx.x*4 + wid;        // 0..69631
  const int fr0 = pair*2;
  const int b0 = fr0/17, t0 = fr0 - b0*17;
  const int fr1 = fr0 + 1;
  const int b1 = fr1/17, t1 = fr1 - b1*17;
  const float* sA = audio + (size_t)b0*3200 + t0*160;
  const float* sB = audio + (size_t)b1*3200 + t1*160;
  float xr[8], xi[8];
  // fused digit-reversed load + window; idx=8L+e -> r9 = baseRev+64e.
  // window w(r9) = 0.5 - 0.5 cos(th0 + e*pi/4): rotor recurrence, 2 transcendentals.
  {
    const int baseRev = ((L & 7) << 3) | (L >> 3);
    float th0 = (float)baseRev * TWO_PI_OVER_512;
    float cw = __cosf(th0), sw = __sinf(th0);
    #pragma unroll
    for (int e = 0; e < 8; e++){
      int r9 = baseRev + (e << 6);
      float w = 0.5f - 0.5f*cw;
      xr[e] = sA[r9]*w;
      xi[e] = sB[r9]*w;
      float nc = C8*(cw - sw), ns = C8*(sw + cw);  // rotate by pi/4
      cw = nc; sw = ns;
    }
  }
  dft8(xr, xi);
  {
    int s0 = 9*L + 5*(L >> 3);                // slot(8L), e contiguous
    #pragma unroll
    for (int e = 0; e < 8; e++) Z[s0 + e] = make_float2(xr[e], xi[e]);
  }
  // stage 1: i = g*64 + j + 8e -> slot = 77g + j + 9e ; W_64^{je} via rotor chain
  {
    int j = L & 7, g = L >> 3;
    int sb = 77*g + j;
    #pragma unroll
    for (int e = 0; e < 8; e++){
      float2 z = Z[sb + 9*e];
      xr[e] = z.x; xi[e] = z.y;
    }
    float ang = (float)j * TWO_PI_OVER_64;
    float c1 = __cosf(ang), s1 = __sinf(ang); // W = c - i s
    float cw = c1, sw = s1;
    #pragma unroll
    for (int e = 1; e < 8; e++){
      float a = xr[e], b = xi[e];
      xr[e] = a*cw + b*sw;
      xi[e] = b*cw - a*sw;
      float nc = cw*c1 - sw*s1, ns = sw*c1 + cw*s1;
      cw = nc; sw = ns;
    }
    dft8(xr, xi);
    #pragma unroll
    for (int e = 0; e < 8; e++) Z[sb + 9*e] = make_float2(xr[e], xi[e]);
  }
  // stage 2: i = L + 64e -> slot = L + (L>>3) + 77e ; lane L ends with Z[k=L+64f]
  {
    int sb = L + (L >> 3);
    #pragma unroll
    for (int e = 0; e < 8; e++){
      float2 z = Z[sb + 77*e];
      xr[e] = z.x; xi[e] = z.y;
    }
    float ang = (float)L * TWO_PI_OVER_512;
    float c1 = __cosf(ang), s1 = __sinf(ang);
    float cw = c1, sw = s1;
    #pragma unroll
    for (int e = 1; e < 8; e++){
      float a = xr[e], b = xi[e];
      xr[e] = a*cw + b*sw;
      xi[e] = b*cw - a*sw;
      float nc = cw*c1 - sw*s1, ns = sw*c1 + cw*s1;
      cw = nc; sw = ns;
    }
    dft8(xr, xi);
  }
  // conj-partner exchange: partner of k=L+64f is lane (64-L)&63, reg 7-f (L>=1)
  float pr[4], pi[4];
  {
    const int partner = (64 - L) & 63;
    #pragma unroll
    for (int f = 0; f < 4; f++){
      pr[f] = __shfl(xr[7-f], partner);
      pi[f] = __shfl(xi[7-f], partner);
    }
    if (L == 0){                              // lane 0: partner regs are own (8-f)&7
      pr[0] = xr[0]; pi[0] = xi[0];
      pr[1] = xr[7]; pi[1] = xi[7];
      pr[2] = xr[6]; pi[2] = xi[6];
      pr[3] = xr[5]; pi[3] = xi[5];
    }
  }
  unsigned short* dA = spec + (size_t)b0*4384 + t0*257;
  unsigned short* dB = spec + (size_t)b1*4384 + t1*257;
  #pragma unroll
  for (int f = 0; f < 4; f++){
    int k = L + 64*f;
    float ar = xr[f] + pr[f], ai = xi[f] - pi[f];
    float br = xi[f] + pi[f], bi = pr[f] - xr[f];
    dA[k] = f2bf(0.5f*sqrtf(ar*ar + ai*ai));
    dB[k] = f2bf(0.5f*sqrtf(br*br + bi*bi));
  }
  if (L == 0){                                // k=256: Xa=Re(Z[256]), Xb=Im(Z[256])
    dA[256] = f2bf(fabsf(xr[4]));
    dB[256] = f2bf(fabsf(xi[4]));
  }
  if (t0 == 0 && L < 15) spec[(size_t)b0*4384 + 4369 + L] = 0;
  if (t1 == 0 && L < 15) spec[(size_t)b1*4384 + 4369 + L] = 0;
}

// ---------------- K4: partial GEMM spec·Dᵀ + moment partials -----------------
// psums layout: [0..4)[8192] = s1 per ks ; [4..8)[8192] = s2 per ks.
__global__ __launch_bounds__(128) void k_gemm(const unsigned short* __restrict__ spec,
    const unsigned short* __restrict__ Dbf, float* __restrict__ part,
    float* __restrict__ psums){
  const int mtile = blockIdx.x;               // 0..255
  const int ks = blockIdx.y;                  // 0..3
  const int wv = threadIdx.x >> 6;
  const int lane = threadIdx.x & 63;
  const int c = lane & 15, q = lane >> 4;
  const int m0 = mtile*32 + wv*16;
  const unsigned short* ap = spec + (size_t)(m0 + c)*4384 + q*8;
  const unsigned short* bp = Dbf + (size_t)c*4384 + q*8;
  const int t0 = ks*35, t1 = (ks == 3) ? 137 : (ks*35 + 35);
  f32x4 acc[8], accS1, accS2;
  #pragma unroll
  for (int nt = 0; nt < 8; nt++) acc[nt] = (f32x4){0.f,0.f,0.f,0.f};
  accS1 = (f32x4){0.f,0.f,0.f,0.f};
  accS2 = (f32x4){0.f,0.f,0.f,0.f};
  bf16x8 onesv;
  #pragma unroll
  for (int i = 0; i < 8; i++) onesv[i] = (short)0x3F80;   // bf16 1.0
  int k0 = t0*32;
  bf16x8 aC = *(const bf16x8*)(ap + k0);
  bf16x8 bC[8];
  #pragma unroll
  for (int nt = 0; nt < 8; nt++)
    bC[nt] = *(const bf16x8*)(bp + (size_t)nt*16*4384 + k0);
  for (int tt = t0; tt < t1; tt++){
    const int tn = (tt + 1 < t1) ? tt + 1 : tt;
    const int kn = tn*32;
    bf16x8 aN = *(const bf16x8*)(ap + kn);
    bf16x8 bN[8];
    #pragma unroll
    for (int nt = 0; nt < 8; nt++)
      bN[nt] = *(const bf16x8*)(bp + (size_t)nt*16*4384 + kn);
    #pragma unroll
    for (int nt = 0; nt < 8; nt++)
      acc[nt] = __builtin_amdgcn_mfma_f32_16x16x32_bf16(aC, bC[nt], acc[nt], 0, 0, 0);
    // moments: s1 = spec·1 ; s2 = diag(spec·specᵀ) — aC is valid as A- and B-frag
    accS1 = __builtin_amdgcn_mfma_f32_16x16x32_bf16(aC, onesv, accS1, 0, 0, 0);
    accS2 = __builtin_amdgcn_mfma_f32_16x16x32_bf16(aC, aC,    accS2, 0, 0, 0);
    aC = aN;
    #pragma unroll
    for (int nt = 0; nt < 8; nt++) bC[nt] = bN[nt];
  }
  float* base = part + (size_t)ks*1048576 + m0 + q*4;
  #pragma unroll
  for (int nt = 0; nt < 8; nt++)
    *(f32x4*)(base + (size_t)(nt*16 + c)*8192) = acc[nt];
  // s1: D[m][n] same for all n -> col c=0 lanes hold rows q*4..q*4+3
  if (c == 0)
    *(f32x4*)(psums + (size_t)ks*8192 + m0 + q*4) = accS1;
  // s2: diagonal m=c held by lane with row q*4+r == c
  if ((c >> 2) == q)
    psums[(size_t)(4 + ks)*8192 + m0 + c] = accS2[c & 3];
}

// ---------------- K5: LCA, 50 iters. rᵀ = G·aᵀ; 4 waves x 32 gram rows ------
// 512 blocks x 256 thr: block = 16 samples; wave wv owns rows [wv*32, wv*32+32).
// a exchanged via double-buffered LDS, ONE barrier per iter.
__global__ __launch_bounds__(256) void k_lca(const float* __restrict__ part,
    const unsigned short* __restrict__ gram_bf, const float* __restrict__ rowsum,
    const float* __restrict__ psums, float* __restrict__ out){
  __shared__ unsigned short A[2][16*136];
  const int tid = threadIdx.x, wv = tid >> 6, lane = tid & 63;
  const int c = lane & 15, q = lane >> 4;
  const int sg = blockIdx.x*16 + c;
  const float S1 = (psums[sg] + psums[8192 + sg])
                 + (psums[16384 + sg] + psums[24576 + sg]);
  const float S2 = (psums[32768 + sg] + psums[40960 + sg])
                 + (psums[49152 + sg] + psums[57344 + sg]);
  const float mus = S1 / 4369.0f;
  float var = (S2 - S1*S1/4369.0f) / 4368.0f;
  var = fmaxf(var, 0.0f);
  const float invs = 1.0f / (sqrtf(var) + 1e-8f);
  const int nb = wv*32;
  bf16x8 Gf[2][4];                            // A-frags of G rows [nb, nb+32)
  #pragma unroll
  for (int rt = 0; rt < 2; rt++)
    #pragma unroll
    for (int kt = 0; kt < 4; kt++)
      Gf[rt][kt] = *(const bf16x8*)(gram_bf + (size_t)(nb + rt*16 + c)*136 + kt*32 + q*8);
  f32x4 U[2], Bb[2];
  #pragma unroll
  for (int rt = 0; rt < 2; rt++){
    #pragma unroll
    for (int r = 0; r < 4; r++){
      int n = nb + rt*16 + q*4 + r;
      float S = part[(size_t)n*8192 + sg]
              + part[(size_t)1048576 + (size_t)n*8192 + sg]
              + part[(size_t)2097152 + (size_t)n*8192 + sg]
              + part[(size_t)3145728 + (size_t)n*8192 + sg];
      Bb[rt][r] = invs * (S - mus * rowsum[n]);
      U[rt][r] = 0.0f;
    }
  }
  for (int it = 0; it < 50; it++){
    unsigned short* Ab = A[it & 1];
    #pragma unroll
    for (int rt = 0; rt < 2; rt++){
      ushort4 pk;
      pk.x = f2bf(sshrink(U[rt][0]));
      pk.y = f2bf(sshrink(U[rt][1]));
      pk.z = f2bf(sshrink(U[rt][2]));
      pk.w = f2bf(sshrink(U[rt][3]));
      *(ushort4*)(Ab + c*136 + nb + rt*16 + q*4) = pk;
    }
    __syncthreads();
    bf16x8 af[4];
    #pragma unroll
    for (int kt = 0; kt < 4; kt++)            // B-frag: aᵀ[k][sample=c]
      af[kt] = *(const bf16x8*)(Ab + c*136 + kt*32 + q*8);
    f32x4 R[2];
    R[0] = (f32x4){0.f,0.f,0.f,0.f};
    R[1] = (f32x4){0.f,0.f,0.f,0.f};
    #pragma unroll
    for (int kt = 0; kt < 4; kt++)            // kt outer: R[0],R[1] chains interleave
      #pragma unroll
      for (int rt = 0; rt < 2; rt++)
        R[rt] = __builtin_amdgcn_mfma_f32_16x16x32_bf16(Gf[rt][kt], af[kt], R[rt], 0, 0, 0);
    #pragma unroll
    for (int rt = 0; rt < 2; rt++){
      #pragma unroll
      for (int r = 0; r < 4; r++){
        float u = U[rt][r];
        U[rt][r] = u + (Bb[rt][r] - u - R[rt][r]) * 0.1f;
      }
    }
  }
  #pragma unroll
  for (int rt = 0; rt < 2; rt++){
    float4 o;
    o.x = sshrink(U[rt][0]);
    o.y = sshrink(U[rt][1]);
    o.z = sshrink(U[rt][2]);
    o.w = sshrink(U[rt][3]);
    *(float4*)(out + (size_t)sg*128 + nb + rt*16 + q*4) = o;
  }
}

// ---------------- launch ----------------
extern "C" void kernel_launch(void* const* d_in, const int* in_sizes, int n_in,
                              void* d_out, int out_size, void* d_ws, size_t ws_size,
                              hipStream_t stream){
  const float* audio = (const float*)d_in[0];   // 8192*3200
  const float* D     = (const float*)d_in[1];   // 128*4369
  float* out = (float*)d_out;                   // 8192*128 f32
  char* ws = (char*)d_ws;
  // workspace layout, total ~90.5 MB
  unsigned short* spec   = (unsigned short*)(ws);               // 71,827,456
  float*          part   = (float*)(ws + 71827456);             // 16,777,216
  unsigned short* Dbf    = (unsigned short*)(ws + 88604672);    // 1,122,304
  unsigned short* gram   = (unsigned short*)(ws + 89726976);    // 34,816
  float*          pgram  = (float*)(ws + 89761792);             // 524,288
  float*          rowsum = (float*)(ws + 90286080);             // 512
  float*          psums  = (float*)(ws + 90286592);             // 262,144 (s1[4] | s2[4])

  k_stft    <<<17408, 256, 0, stream>>>(audio, spec);
  k_dprep   <<<128, 256, 0, stream>>>(D, Dbf, rowsum);
  k_gram_mm <<<dim3(8, 8, 1), 64, 0, stream>>>(Dbf, pgram);
  k_gram_fin<<<128, 128, 0, stream>>>(pgram, gram);
  k_gemm    <<<dim3(256, 4, 1), 128, 0, stream>>>(spec, Dbf, part, psums);
  k_lca     <<<512, 256, 0, stream>>>(part, gram, rowsum, psums, out);
}